// Round 7
// baseline (148.574 us; speedup 1.0000x reference)
//
#include <hip/hip_runtime.h>
#include <hip/hip_bf16.h>
#include <cstddef>
#include <cstdint>

typedef _Float16 half_t;
typedef _Float16 half8  __attribute__((ext_vector_type(8)));
typedef _Float16 half4v __attribute__((ext_vector_type(4)));
typedef float    f32x4  __attribute__((ext_vector_type(4)));

#define SCALE 0.17677669529663687f   // 1/sqrt(32)

// workspace layout (bytes):
//   [0,      221184)  wqfrag fragment-major qkv weights fp16
//                     unit u16 = ((ct*6+ks)*4+g)*16+c -> 8 halves (16B),
//                     element = w_qkv[(16ct+c)*192 + ks*32 + g*8 + e]
//   [221184, 294912)  wofrag fragment-major out-proj weights fp16 (same scheme)
//   [294912, 491520)  mb16[4][6][64][64] fp16 masked rel-pos bias table

// ---------------------------------------------------------------------------
__global__ __launch_bounds__(256) void convert_w(
    const float* __restrict__ w_qkv, const float* __restrict__ w_out,
    half_t* __restrict__ wq, half_t* __restrict__ wo)
{
    int i = blockIdx.x * 256 + threadIdx.x;
    if (i < 110592) {
        int u8 = i >> 3, e = i & 7;
        int c  = u8 & 15;
        int g  = (u8 >> 4) & 3;
        int ks = (u8 >> 6) % 6;
        int ct = u8 / 384;
        wq[i] = (half_t)w_qkv[(16 * ct + c) * 192 + ks * 32 + g * 8 + e];
    } else {
        int j = i - 110592;
        if (j < 36864) {
            int u8 = j >> 3, e = j & 7;
            int c  = u8 & 15;
            int g  = (u8 >> 4) & 3;
            int ks = (u8 >> 6) % 6;
            int q  = u8 / 384;
            wo[j] = (half_t)w_out[(16 * q + c) * 192 + ks * 32 + g * 8 + e];
        }
    }
}

// ---------------------------------------------------------------------------
// Masked relative-position bias table: mb[4][6][64][64] fp16.
// Mask class mc = 2*(nh==7) + (nw==7). Masked / padded entries = -60000.
// ---------------------------------------------------------------------------
__global__ __launch_bounds__(256) void build_bias(
    const float* __restrict__ pos_enc, half_t* __restrict__ mb)
{
    int idx = blockIdx.x * 256 + threadIdx.x;   // < 98304
    int j   = idx & 63;
    int i   = (idx >> 6) & 63;
    int hmc = idx >> 12;
    int h   = hmc % 6, mc = hmc / 6;
    float v = -60000.f;
    if (i < 49 && j < 49) {
        int yi = i / 7, xi = i - 7 * yi;
        int yj = j / 7, xj = j - 7 * yj;
        int ri = ((mc & 2) ? (yi < 4 ? 1 : 2) : 0) * 3 + ((mc & 1) ? (xi < 4 ? 1 : 2) : 0);
        int rj = ((mc & 2) ? (yj < 4 ? 1 : 2) : 0) * 3 + ((mc & 1) ? (xj < 4 ? 1 : 2) : 0);
        if (ri == rj) v = pos_enc[h * 169 + (yi - yj + 6) * 13 + (xi - xj + 6)];
    }
    mb[idx] = (half_t)v;
}

// ---------------------------------------------------------------------------
// Fully fused: gather+shift -> QKV -> attention -> out-proj -> un-shift.
// grid = 2048 (one window per block), 512 threads = 8 waves.
// QKV role:       wave = (cf = wave>>1 in [0,4), mh = wave&1): 3 col-tiles,
//                 32 tokens (M-tiles 2mh, 2mh+1).
// attn/proj role: wave = (ti = wave&3, hf = wave>>2).
// qkv tensors double-buffered in LDS across the 3 head-pair iterations.
// ---------------------------------------------------------------------------
__global__ __launch_bounds__(512, 4) void swin_fused(
    const float*  __restrict__ x,
    const half_t* __restrict__ wqfrag,
    const float*  __restrict__ b_qkv,
    const half_t* __restrict__ mb16,
    const half_t* __restrict__ wofrag,
    const float*  __restrict__ b_out,
    float* __restrict__ out)
{
    __shared__ half_t sQ[2][2][64][34];            // [buf][hh][tok][d] (+2 pad)
    __shared__ half_t sK[2][2][64][34];
    __shared__ half_t sV2[2][2][4][2][16][16];     // [buf][hh][tj][dt][c][4g+r]
    __shared__ half_t sA2[12][64][16];             // [kt][tok][d%16]  (O, frag-major)

    const int w    = blockIdx.x;
    const int b    = w >> 6, win = w & 63, nh = win >> 3, nw = win & 7;
    const int tid  = threadIdx.x;
    const int wave = tid >> 6, lane = tid & 63;
    const int c    = lane & 15, g = lane >> 4;
    // QKV roles
    const int cf = wave >> 1, mh = wave & 1;
    // attention / out-proj roles
    const int ti = wave & 3, hf = wave >> 2;
    const int i_tok = 16 * ti + c;
    const int mc = 2 * (nh == 7) + (nw == 7);

    // ---- shifted-window gather of X rows into A-fragments (32 tokens) ----
    half8 xf[2][6];
    #pragma unroll
    for (int t = 0; t < 2; ++t) {
        int tok = 32 * mh + 16 * t + c;
        if (tok < 49) {
            int ty = tok / 7, tx = tok - ty * 7;
            int sy = nh * 7 + ty + 3; if (sy >= 56) sy -= 56;
            int sx = nw * 7 + tx + 3; if (sx >= 56) sx -= 56;
            const float* xr = x + ((size_t)b * 3136 + sy * 56 + sx) * 192 + g * 8;
            #pragma unroll
            for (int ks = 0; ks < 6; ++ks) {
                float4 v0 = *(const float4*)(xr + ks * 32);
                float4 v1 = *(const float4*)(xr + ks * 32 + 4);
                xf[t][ks] = (half8){(half_t)v0.x, (half_t)v0.y, (half_t)v0.z, (half_t)v0.w,
                                    (half_t)v1.x, (half_t)v1.y, (half_t)v1.z, (half_t)v1.w};
            }
        } else {
            #pragma unroll
            for (int ks = 0; ks < 6; ++ks)
                xf[t][ks] = (half8){(half_t)0.f, (half_t)0.f, (half_t)0.f, (half_t)0.f,
                                    (half_t)0.f, (half_t)0.f, (half_t)0.f, (half_t)0.f};
        }
    }

    #pragma unroll
    for (int pp = 0; pp < 3; ++pp) {
        const int buf = pp & 1;

        // ---- QKV slice for heads {2pp, 2pp+1}: 3 col-tiles per wave ------
        {
            f32x4 acc[3][2];
            #pragma unroll
            for (int q = 0; q < 3; ++q) {
                acc[q][0] = (f32x4){0.f, 0.f, 0.f, 0.f};
                acc[q][1] = (f32x4){0.f, 0.f, 0.f, 0.f};
            }
            #pragma unroll
            for (int ks = 0; ks < 6; ++ks) {
                #pragma unroll
                for (int q = 0; q < 3; ++q) {
                    const int cc   = 3 * cf + q;
                    const int kind = cc >> 2, sub = cc & 3;
                    const int hh   = sub >> 1, dh = sub & 1;
                    const int ct   = kind * 12 + (2 * pp + hh) * 2 + dh;
                    half8 bF = *(const half8*)(wqfrag + (((size_t)ct * 6 + ks) * 64 + g * 16 + c) * 8);
                    acc[q][0] = __builtin_amdgcn_mfma_f32_16x16x32_f16(xf[0][ks], bF, acc[q][0], 0, 0, 0);
                    acc[q][1] = __builtin_amdgcn_mfma_f32_16x16x32_f16(xf[1][ks], bF, acc[q][1], 0, 0, 0);
                }
            }
            #pragma unroll
            for (int q = 0; q < 3; ++q) {
                const int cc   = 3 * cf + q;
                const int kind = cc >> 2, sub = cc & 3;
                const int hh   = sub >> 1, dh = sub & 1;
                const int ct   = kind * 12 + (2 * pp + hh) * 2 + dh;
                const float bias = b_qkv[16 * ct + c];
                if (kind == 2) {
                    #pragma unroll
                    for (int t = 0; t < 2; ++t) {
                        half4v pv = (half4v){(half_t)(acc[q][t][0] + bias), (half_t)(acc[q][t][1] + bias),
                                             (half_t)(acc[q][t][2] + bias), (half_t)(acc[q][t][3] + bias)};
                        *(half4v*)&sV2[buf][hh][2 * mh + t][dh][c][4 * g] = pv;
                    }
                } else {
                    #pragma unroll
                    for (int t = 0; t < 2; ++t) {
                        #pragma unroll
                        for (int r = 0; r < 4; ++r) {
                            int tok = 32 * mh + 16 * t + 4 * g + r;
                            half_t vv = (half_t)(acc[q][t][r] + bias);
                            if (kind == 0) sQ[buf][hh][tok][dh * 16 + c] = vv;
                            else           sK[buf][hh][tok][dh * 16 + c] = vv;
                        }
                    }
                }
            }
        }
        __syncthreads();

        // ---- attention: wave (ti, hf), head h = 2pp + hf ------------------
        {
            const int h = 2 * pp + hf;
            const half_t* mrow = mb16 + ((size_t)(mc * 6 + h) * 64 + i_tok) * 64;
            half4v bfr[4];
            #pragma unroll
            for (int tj = 0; tj < 4; ++tj)
                bfr[tj] = *(const half4v*)(mrow + 16 * tj + 4 * g);

            half8 qf = *(const half8*)&sQ[buf][hf][i_tok][g * 8];
            f32x4 st[4];
            #pragma unroll
            for (int tj = 0; tj < 4; ++tj) {
                half8 kf = *(const half8*)&sK[buf][hf][16 * tj + c][g * 8];
                f32x4 z = (f32x4){0.f, 0.f, 0.f, 0.f};
                st[tj] = __builtin_amdgcn_mfma_f32_16x16x32_f16(kf, qf, z, 0, 0, 0);
            }
            #pragma unroll
            for (int tj = 0; tj < 4; ++tj)
                #pragma unroll
                for (int r = 0; r < 4; ++r)
                    st[tj][r] = st[tj][r] * SCALE + (float)bfr[tj][r];

            float m = st[0][0];
            #pragma unroll
            for (int tj = 0; tj < 4; ++tj)
                #pragma unroll
                for (int r = 0; r < 4; ++r) m = fmaxf(m, st[tj][r]);
            m = fmaxf(m, __shfl_xor(m, 16));
            m = fmaxf(m, __shfl_xor(m, 32));
            float sum = 0.f;
            #pragma unroll
            for (int tj = 0; tj < 4; ++tj)
                #pragma unroll
                for (int r = 0; r < 4; ++r) {
                    float e = __expf(st[tj][r] - m);
                    st[tj][r] = e;
                    sum += e;
                }
            sum += __shfl_xor(sum, 16);
            sum += __shfl_xor(sum, 32);
            float inv = 1.0f / sum;
            half4v pa[4];
            #pragma unroll
            for (int tj = 0; tj < 4; ++tj)
                pa[tj] = (half4v){(half_t)(st[tj][0] * inv), (half_t)(st[tj][1] * inv),
                                  (half_t)(st[tj][2] * inv), (half_t)(st[tj][3] * inv)};

            f32x4 o0 = (f32x4){0.f, 0.f, 0.f, 0.f};
            f32x4 o1 = (f32x4){0.f, 0.f, 0.f, 0.f};
            #pragma unroll
            for (int tj = 0; tj < 4; ++tj) {
                half4v v0 = *(const half4v*)&sV2[buf][hf][tj][0][c][4 * g];
                half4v v1 = *(const half4v*)&sV2[buf][hf][tj][1][c][4 * g];
                o0 = __builtin_amdgcn_mfma_f32_16x16x16f16(v0, pa[tj], o0, 0, 0, 0);
                o1 = __builtin_amdgcn_mfma_f32_16x16x16f16(v1, pa[tj], o1, 0, 0, 0);
            }
            *(half4v*)&sA2[2 * h][i_tok][4 * g] =
                (half4v){(half_t)o0[0], (half_t)o0[1], (half_t)o0[2], (half_t)o0[3]};
            *(half4v*)&sA2[2 * h + 1][i_tok][4 * g] =
                (half4v){(half_t)o1[0], (half_t)o1[1], (half_t)o1[2], (half_t)o1[3]};
        }
    }
    __syncthreads();

    // ---- out-projection + un-shift scatter -------------------------------
    {
        f32x4 pacc[6];
        float bo[6];
        #pragma unroll
        for (int q = 0; q < 6; ++q) {
            pacc[q] = (f32x4){0.f, 0.f, 0.f, 0.f};
            bo[q] = b_out[16 * (6 * hf + q) + c];
        }
        #pragma unroll
        for (int ks = 0; ks < 6; ++ks) {
            half8 aF = *(const half8*)&sA2[2 * ks + (g >> 1)][i_tok][(g & 1) * 8];
            #pragma unroll
            for (int q = 0; q < 6; ++q) {
                int ct = 6 * hf + q;
                half8 bF = *(const half8*)(wofrag + ((size_t)(ct * 6 + ks) * 64 + lane) * 8);
                pacc[q] = __builtin_amdgcn_mfma_f32_16x16x32_f16(aF, bF, pacc[q], 0, 0, 0);
            }
        }
        #pragma unroll
        for (int r = 0; r < 4; ++r) {
            int tok = 16 * ti + g * 4 + r;
            if (tok < 49) {
                int ty = tok / 7, tx = tok - ty * 7;
                int dy = nh * 7 + ty + 3; if (dy >= 56) dy -= 56;
                int dx = nw * 7 + tx + 3; if (dx >= 56) dx -= 56;
                float* op = out + ((size_t)b * 3136 + dy * 56 + dx) * 192;
                #pragma unroll
                for (int q = 0; q < 6; ++q)
                    op[16 * (6 * hf + q) + c] = pacc[q][r] + bo[q];
            }
        }
    }
}

// ---------------------------------------------------------------------------
extern "C" void kernel_launch(void* const* d_in, const int* in_sizes, int n_in,
                              void* d_out, int out_size, void* d_ws, size_t ws_size,
                              hipStream_t stream) {
    const float* x       = (const float*)d_in[0];
    const float* w_qkv   = (const float*)d_in[1];
    const float* b_qkv   = (const float*)d_in[2];
    const float* w_out   = (const float*)d_in[3];
    const float* b_out   = (const float*)d_in[4];
    const float* pos_enc = (const float*)d_in[5];
    float* out = (float*)d_out;

    half_t* wqf  = (half_t*)d_ws;
    half_t* wof  = (half_t*)((char*)d_ws + 221184);
    half_t* mb16 = (half_t*)((char*)d_ws + 294912);

    convert_w<<<dim3(576), dim3(256), 0, stream>>>(w_qkv, w_out, wqf, wof);
    build_bias<<<dim3(384), dim3(256), 0, stream>>>(pos_enc, mb16);
    swin_fused<<<dim3(2048), dim3(512), 0, stream>>>(
        x, wqf, b_qkv, mb16, wof, b_out, out);
}

// Round 8
// 130.711 us; speedup vs baseline: 1.1367x; 1.1367x over previous
//
#include <hip/hip_runtime.h>
#include <hip/hip_bf16.h>
#include <cstddef>
#include <cstdint>

typedef _Float16 half_t;
typedef _Float16 half8  __attribute__((ext_vector_type(8)));
typedef _Float16 half4v __attribute__((ext_vector_type(4)));
typedef float    f32x4  __attribute__((ext_vector_type(4)));

#define SCALE 0.17677669529663687f   // 1/sqrt(32)

// workspace layout (bytes):
//   [0,        221184)   wqfrag  fragment-major qkv weights fp16 (K1 input)
//                        -- after K1 runs, the first 196608 B are overwritten
//                           by mb16[4][6][64][64] fp16 masked-bias table (K2)
//   [221184,   294912)   wofrag  fragment-major out-proj weights fp16
//   [294912,  38830080)  q_ws    [2048][6][49][32] fp16
//   [38830080,77365248)  k_ws    [2048][6][49][32] fp16
//   [77365248,118259712) vt_ws   [2048][6][32][52] fp16

// ---------------------------------------------------------------------------
__global__ __launch_bounds__(256) void convert_w(
    const float* __restrict__ w_qkv, const float* __restrict__ w_out,
    half_t* __restrict__ wq, half_t* __restrict__ wo)
{
    int i = blockIdx.x * 256 + threadIdx.x;
    if (i < 110592) {
        int u8 = i >> 3, e = i & 7;
        int c  = u8 & 15;
        int g  = (u8 >> 4) & 3;
        int ks = (u8 >> 6) % 6;
        int ct = u8 / 384;
        wq[i] = (half_t)w_qkv[(16 * ct + c) * 192 + ks * 32 + g * 8 + e];
    } else {
        int j = i - 110592;
        if (j < 36864) {
            int u8 = j >> 3, e = j & 7;
            int c  = u8 & 15;
            int g  = (u8 >> 4) & 3;
            int ks = (u8 >> 6) % 6;
            int q  = u8 / 384;
            wo[j] = (half_t)w_out[(16 * q + c) * 192 + ks * 32 + g * 8 + e];
        }
    }
}

// ---------------------------------------------------------------------------
// Masked relative-position bias table: mb[4][6][64][64] fp16.
// Mask class mc = 2*(nh==7) + (nw==7). Masked / padded entries = -60000.
// ---------------------------------------------------------------------------
__global__ __launch_bounds__(256) void build_bias(
    const float* __restrict__ pos_enc, half_t* __restrict__ mb)
{
    int idx = blockIdx.x * 256 + threadIdx.x;   // < 98304
    int j   = idx & 63;
    int i   = (idx >> 6) & 63;
    int hmc = idx >> 12;
    int h   = hmc % 6, mc = hmc / 6;
    float v = -60000.f;
    if (i < 49 && j < 49) {
        int yi = i / 7, xi = i - 7 * yi;
        int yj = j / 7, xj = j - 7 * yj;
        int ri = ((mc & 2) ? (yi < 4 ? 1 : 2) : 0) * 3 + ((mc & 1) ? (xi < 4 ? 1 : 2) : 0);
        int rj = ((mc & 2) ? (yj < 4 ? 1 : 2) : 0) * 3 + ((mc & 1) ? (xj < 4 ? 1 : 2) : 0);
        if (ri == rj) v = pos_enc[h * 169 + (yi - yj + 6) * 13 + (xi - xj + 6)];
    }
    mb[idx] = (half_t)v;
}

// ---------------------------------------------------------------------------
// K1: QKV projection. 512 blocks x 512 threads; block = 4 windows.
// Weights staged through LDS in 6 chunks of 36KB, shared by all 8 waves.
// (unchanged from round 6 — proven ~50 us)
// ---------------------------------------------------------------------------
__global__ __launch_bounds__(512, 4) void swin_qkv(
    const float*  __restrict__ x,
    const half_t* __restrict__ wqfrag,
    const float*  __restrict__ b_qkv,
    half_t* __restrict__ qws,
    half_t* __restrict__ kws,
    half_t* __restrict__ vtws)
{
    __shared__ half_t sW[2304 * 8];   // 36864 B: one 6-col-tile chunk

    const int tid  = threadIdx.x;
    const int wave = tid >> 6, lane = tid & 63;
    const int c    = lane & 15, g = lane >> 4;
    const int widx = wave >> 1, mh = wave & 1;
    const int w    = blockIdx.x * 4 + widx;
    const int b    = w >> 6, win = w & 63, nh = win >> 3, nw = win & 7;

    half8 xf[2][6];
    #pragma unroll
    for (int t = 0; t < 2; ++t) {
        int tok = 32 * mh + 16 * t + c;
        if (tok < 49) {
            int ty = tok / 7, tx = tok - ty * 7;
            int sy = nh * 7 + ty + 3; if (sy >= 56) sy -= 56;
            int sx = nw * 7 + tx + 3; if (sx >= 56) sx -= 56;
            const float* xr = x + ((size_t)b * 3136 + sy * 56 + sx) * 192 + g * 8;
            #pragma unroll
            for (int ks = 0; ks < 6; ++ks) {
                float4 v0 = *(const float4*)(xr + ks * 32);
                float4 v1 = *(const float4*)(xr + ks * 32 + 4);
                xf[t][ks] = (half8){(half_t)v0.x, (half_t)v0.y, (half_t)v0.z, (half_t)v0.w,
                                    (half_t)v1.x, (half_t)v1.y, (half_t)v1.z, (half_t)v1.w};
            }
        } else {
            #pragma unroll
            for (int ks = 0; ks < 6; ++ks)
                xf[t][ks] = (half8){(half_t)0.f, (half_t)0.f, (half_t)0.f, (half_t)0.f,
                                    (half_t)0.f, (half_t)0.f, (half_t)0.f, (half_t)0.f};
        }
    }

    #pragma unroll
    for (int ch = 0; ch < 6; ++ch) {
        #pragma unroll
        for (int p = 0; p < 5; ++p) {
            int u = tid + p * 512;
            if (u < 2304) {
                const half_t* src = wqfrag + ((size_t)ch * 2304 + u) * 8;
                half_t* dst = &sW[u * 8];
                __builtin_amdgcn_global_load_lds(
                    (const __attribute__((address_space(1))) unsigned int*)src,
                    (__attribute__((address_space(3))) unsigned int*)dst, 16, 0, 0);
            }
        }
        __syncthreads();

        #pragma unroll
        for (int ctl = 0; ctl < 6; ++ctl) {
            const int ct = ch * 6 + ctl;
            f32x4 a0 = (f32x4){0.f, 0.f, 0.f, 0.f};
            f32x4 a1 = (f32x4){0.f, 0.f, 0.f, 0.f};
            #pragma unroll
            for (int ks = 0; ks < 6; ++ks) {
                half8 bF = *(const half8*)&sW[(ctl * 384 + ks * 64 + g * 16 + c) * 8];
                a0 = __builtin_amdgcn_mfma_f32_16x16x32_f16(xf[0][ks], bF, a0, 0, 0, 0);
                a1 = __builtin_amdgcn_mfma_f32_16x16x32_f16(xf[1][ks], bF, a1, 0, 0, 0);
            }
            const int kind = ct / 12, rem = ct - 12 * kind;
            const int h = rem >> 1, d = ((rem & 1) << 4) + c;
            const float bias = b_qkv[16 * ct + c];
            const int wh = w * 6 + h;
            if (kind == 2) {
                #pragma unroll
                for (int t = 0; t < 2; ++t) {
                    f32x4 a = t ? a1 : a0;
                    int tok0 = 32 * mh + 16 * t + 4 * g;
                    if (tok0 <= 48) {
                        half4v pv = (half4v){(half_t)(a[0] + bias), (half_t)(a[1] + bias),
                                             (half_t)(a[2] + bias), (half_t)(a[3] + bias)};
                        *(half4v*)(vtws + (size_t)(wh * 32 + d) * 52 + tok0) = pv;
                    }
                }
            } else {
                half_t* dstp = (kind == 0) ? qws : kws;
                #pragma unroll
                for (int t = 0; t < 2; ++t) {
                    f32x4 a = t ? a1 : a0;
                    #pragma unroll
                    for (int r = 0; r < 4; ++r) {
                        int tok = 32 * mh + 16 * t + 4 * g + r;
                        if (tok < 49)
                            dstp[((size_t)wh * 49 + tok) * 32 + d] = (half_t)(a[r] + bias);
                    }
                }
            }
        }
        __syncthreads();
    }
}

// ---------------------------------------------------------------------------
// K2: attention (3 heads/wave; K staged in LDS; q/bias/V prefetched one head
// ahead in statically-indexed register buffers) + out-projection through a
// conflict-free frag-major LDS O-buffer + un-shift scatter.
// grid = 2048, 512 threads = 8 waves; wave (ti, hf): heads h = 3*hf + p.
// ---------------------------------------------------------------------------
__global__ __launch_bounds__(512, 4) void swin_attn_proj(
    const half_t* __restrict__ qws,
    const half_t* __restrict__ kws,
    const half_t* __restrict__ vtws,
    const half_t* __restrict__ mb16,
    const half_t* __restrict__ wofrag,
    const float*  __restrict__ b_out,
    float* __restrict__ out)
{
    __shared__ __align__(16) half_t sK[1536 * 8];        // 24576 B (18816 used)
    __shared__ __align__(16) half_t sAf[6 * 4 * 64 * 8]; // 24576 B frag-major O

    const int w    = blockIdx.x;
    const int b    = w >> 6, win = w & 63, nh = win >> 3, nw = win & 7;
    const int tid  = threadIdx.x;
    const int wave = tid >> 6, lane = tid & 63;
    const int c    = lane & 15, g = lane >> 4;
    const int ti   = wave & 3, hf = wave >> 2;
    const int i_tok = 16 * ti + c;
    const int mc   = 2 * (nh == 7) + (nw == 7);

    // ---- stage this window's K (6 heads x 49x32 fp16) into LDS linearly --
    {
        const half_t* src = kws + (size_t)w * 9408;
        #pragma unroll
        for (int rnd = 0; rnd < 3; ++rnd) {
            int u = tid + rnd * 512;   // up to 1536 units (tail overread is benign)
            __builtin_amdgcn_global_load_lds(
                (const __attribute__((address_space(1))) unsigned int*)(src + u * 8),
                (__attribute__((address_space(3))) unsigned int*)(&sK[u * 8]), 16, 0, 0);
        }
    }

    half8  qA, qB;
    half4v bA[4], bB[4];
    half4v vA[8], vB[8];

#define LOADH(QF, BF, VF, hh) do {                                              \
        const int wh_ = w * 6 + (hh);                                           \
        QF = *(const half8*)(qws + ((size_t)wh_ * 49 + i_tok) * 32 + g * 8);    \
        const half_t* mrow_ = mb16 + ((size_t)(mc * 6 + (hh)) * 64 + i_tok) * 64; \
        _Pragma("unroll")                                                       \
        for (int tj_ = 0; tj_ < 4; ++tj_)                                       \
            BF[tj_] = *(const half4v*)(mrow_ + 16 * tj_ + 4 * g);               \
        const half_t* vh_ = vtws + (size_t)wh_ * 1664;                          \
        _Pragma("unroll")                                                       \
        for (int tj_ = 0; tj_ < 4; ++tj_) {                                     \
            VF[2 * tj_]     = *(const half4v*)(vh_ + c * 52 + 16 * tj_ + 4 * g);        \
            VF[2 * tj_ + 1] = *(const half4v*)(vh_ + (16 + c) * 52 + 16 * tj_ + 4 * g); \
        }                                                                       \
    } while (0)

    // prefetch head 0 while staging is in flight
    LOADH(qA, bA, vA, 3 * hf);
    __syncthreads();   // staging (and prefetch) complete

    #pragma unroll
    for (int p = 0; p < 3; ++p) {
        const int h = 3 * hf + p;
        // prefetch next head into the other buffer set
        if (p == 0) LOADH(qB, bB, vB, h + 1);
        if (p == 1) LOADH(qA, bA, vA, h + 1);

        const half8&  qf = (p == 1) ? qB : qA;
        const half4v* bf = (p == 1) ? bB : bA;
        const half4v* vf = (p == 1) ? vB : vA;

        // K fragments from LDS (stride-64B rows: wire-speed ds_read_b128)
        half8 kf[4];
        #pragma unroll
        for (int tj = 0; tj < 4; ++tj)
            kf[tj] = *(const half8*)&sK[((size_t)h * 49 + 16 * tj + c) * 32 + g * 8];

        // S^T = K * Q^T ; lane holds S[i_tok][j = 16tj + 4g + r]
        f32x4 st[4];
        #pragma unroll
        for (int tj = 0; tj < 4; ++tj) {
            f32x4 z = (f32x4){0.f, 0.f, 0.f, 0.f};
            st[tj] = __builtin_amdgcn_mfma_f32_16x16x32_f16(kf[tj], qf, z, 0, 0, 0);
        }
        #pragma unroll
        for (int tj = 0; tj < 4; ++tj)
            #pragma unroll
            for (int r = 0; r < 4; ++r)
                st[tj][r] = st[tj][r] * SCALE + (float)bf[tj][r];

        // softmax (16 in-register + lane-pairs 16, 32 apart)
        float m = st[0][0];
        #pragma unroll
        for (int tj = 0; tj < 4; ++tj)
            #pragma unroll
            for (int r = 0; r < 4; ++r) m = fmaxf(m, st[tj][r]);
        m = fmaxf(m, __shfl_xor(m, 16));
        m = fmaxf(m, __shfl_xor(m, 32));
        float sum = 0.f;
        #pragma unroll
        for (int tj = 0; tj < 4; ++tj)
            #pragma unroll
            for (int r = 0; r < 4; ++r) {
                float e = __expf(st[tj][r] - m);
                st[tj][r] = e;
                sum += e;
            }
        sum += __shfl_xor(sum, 16);
        sum += __shfl_xor(sum, 32);
        float inv = 1.0f / sum;
        half4v pa[4];
        #pragma unroll
        for (int tj = 0; tj < 4; ++tj)
            pa[tj] = (half4v){(half_t)(st[tj][0] * inv), (half_t)(st[tj][1] * inv),
                              (half_t)(st[tj][2] * inv), (half_t)(st[tj][3] * inv)};

        // PV: O^T = V^T * P^T
        f32x4 o0 = (f32x4){0.f, 0.f, 0.f, 0.f};
        f32x4 o1 = (f32x4){0.f, 0.f, 0.f, 0.f};
        #pragma unroll
        for (int tj = 0; tj < 4; ++tj) {
            o0 = __builtin_amdgcn_mfma_f32_16x16x16f16(vf[2 * tj],     pa[tj], o0, 0, 0, 0);
            o1 = __builtin_amdgcn_mfma_f32_16x16x16f16(vf[2 * tj + 1], pa[tj], o1, 0, 0, 0);
        }
        // frag-major O store: element (i_tok, 32h+16dt+4g+r) at
        // half-index ((h*4+ti)*64 + (2dt+(g>>1))*16 + c)*8 + (g&1)*4 + r
        {
            int base = (((h * 4 + ti) * 64 + (g >> 1) * 16 + c) << 3) + (g & 1) * 4;
            *(half4v*)&sAf[base] =
                (half4v){(half_t)o0[0], (half_t)o0[1], (half_t)o0[2], (half_t)o0[3]};
            *(half4v*)&sAf[base + 256] =
                (half4v){(half_t)o1[0], (half_t)o1[1], (half_t)o1[2], (half_t)o1[3]};
        }
    }
#undef LOADH
    __syncthreads();

    // ---- out-projection + un-shift scatter -------------------------------
    {
        f32x4 pacc[6];
        float bo[6];
        #pragma unroll
        for (int q = 0; q < 6; ++q) {
            pacc[q] = (f32x4){0.f, 0.f, 0.f, 0.f};
            bo[q] = b_out[16 * (6 * hf + q) + c];
        }
        #pragma unroll
        for (int ks = 0; ks < 6; ++ks) {
            half8 aF = *(const half8*)&sAf[((ks * 4 + ti) * 64 + lane) * 8];
            #pragma unroll
            for (int q = 0; q < 6; ++q) {
                int ct = 6 * hf + q;
                half8 bF = *(const half8*)(wofrag + ((size_t)(ct * 6 + ks) * 64 + lane) * 8);
                pacc[q] = __builtin_amdgcn_mfma_f32_16x16x32_f16(aF, bF, pacc[q], 0, 0, 0);
            }
        }
        #pragma unroll
        for (int r = 0; r < 4; ++r) {
            int tok = 16 * ti + g * 4 + r;
            if (tok < 49) {
                int ty = tok / 7, tx = tok - ty * 7;
                int dy = nh * 7 + ty + 3; if (dy >= 56) dy -= 56;
                int dx = nw * 7 + tx + 3; if (dx >= 56) dx -= 56;
                float* op = out + ((size_t)b * 3136 + dy * 56 + dx) * 192;
                #pragma unroll
                for (int q = 0; q < 6; ++q)
                    op[16 * (6 * hf + q) + c] = pacc[q][r] + bo[q];
            }
        }
    }
}

// ---------------------------------------------------------------------------
extern "C" void kernel_launch(void* const* d_in, const int* in_sizes, int n_in,
                              void* d_out, int out_size, void* d_ws, size_t ws_size,
                              hipStream_t stream) {
    const float* x       = (const float*)d_in[0];
    const float* w_qkv   = (const float*)d_in[1];
    const float* b_qkv   = (const float*)d_in[2];
    const float* w_out   = (const float*)d_in[3];
    const float* b_out   = (const float*)d_in[4];
    const float* pos_enc = (const float*)d_in[5];
    float* out = (float*)d_out;

    half_t* wqf  = (half_t*)d_ws;                       // K1 weights (then mb16)
    half_t* mb16 = (half_t*)d_ws;                       // bias table (after K1)
    half_t* wof  = (half_t*)((char*)d_ws + 221184);
    half_t* qws  = (half_t*)((char*)d_ws + 294912);
    half_t* kws  = (half_t*)((char*)d_ws + 38830080);
    half_t* vtws = (half_t*)((char*)d_ws + 77365248);

    convert_w<<<dim3(576), dim3(256), 0, stream>>>(w_qkv, w_out, wqf, wof);
    swin_qkv<<<dim3(512), dim3(512), 0, stream>>>(x, wqf, b_qkv, qws, kws, vtws);
    build_bias<<<dim3(384), dim3(256), 0, stream>>>(pos_enc, mb16);
    swin_attn_proj<<<dim3(2048), dim3(512), 0, stream>>>(
        qws, kws, vtws, mb16, wof, b_out, out);
}